// Round 1
// baseline (419.804 us; speedup 1.0000x reference)
//
#include <hip/hip_runtime.h>
#include <cstdint>
#include <cstddef>

#define B_ 256
#define M_ 96
#define W_ 128
#define D_ 512

typedef _Float16 f16;
typedef __attribute__((ext_vector_type(8))) _Float16 f16x8;
typedef __attribute__((ext_vector_type(2))) _Float16 f16x2;
typedef __attribute__((ext_vector_type(4))) float f32x4;

typedef __attribute__((address_space(3))) void lds_void;
typedef const __attribute__((address_space(1))) void glb_void;

__device__ __forceinline__ void gload_lds16(const void* g, void* l) {
  __builtin_amdgcn_global_load_lds((glb_void*)g, (lds_void*)l, 16, 0, 0);
}

// ---------------- f32 -> f16 conversion (8 elems/thread) ----------------
__global__ void cvt_f32_f16(const float* __restrict__ in, f16* __restrict__ out, int n8) {
  int i = blockIdx.x * 256 + threadIdx.x;
  if (i >= n8) return;
  const float4* p = (const float4*)in + (size_t)i * 2;
  float4 a = p[0], b = p[1];
  f16x8 o = { (f16)a.x, (f16)a.y, (f16)a.z, (f16)a.w,
              (f16)b.x, (f16)b.y, (f16)b.z, (f16)b.w };
  ((f16x8*)out)[i] = o;
}

// ---------------- BT GEMM, 128x128 tile, BK=64, f16 MFMA ----------------
// MODE 0: out0[m*512 + col] = (f16)(acc + bias[col])           (k GEMM)
// MODE 1: cols [0,512): q -> out0 ; [512,1024): sigmoid -> out1 ; [1024,1536): tanh -> out2
template<int MODE>
__global__ __launch_bounds__(256, 2)
void gemm_bt(const f16* __restrict__ A, const f16* __restrict__ Bm,
             const float* __restrict__ bias,
             f16* __restrict__ out0, f16* __restrict__ out1, f16* __restrict__ out2)
{
  constexpr int K = 512;
  constexpr int BK = 64;
  __shared__ f16 As[128 * BK];
  __shared__ f16 Bs[128 * BK];
  const int tid = threadIdx.x;
  const int lane = tid & 63;
  const int wv = tid >> 6;
  const int wr = wv >> 1, wc = wv & 1;
  const int bm = blockIdx.x, bn = blockIdx.y;
  const f16* Ab = A + (size_t)bm * 128 * K;
  const f16* Bb = Bm + (size_t)bn * 128 * K;

  f32x4 acc[4][4] = {};

  const int r0 = tid >> 3;          // staging row within 32-row group
  const int c0 = (tid & 7) * 8;     // staging col (f16 units)

  for (int kk = 0; kk < K / BK; ++kk) {
    const int kbase = kk * BK;
#pragma unroll
    for (int p = 0; p < 4; ++p) {
      int row = p * 32 + r0;
      gload_lds16(Ab + (size_t)row * K + kbase + c0, As + row * BK + c0);
    }
#pragma unroll
    for (int p = 0; p < 4; ++p) {
      int row = p * 32 + r0;
      gload_lds16(Bb + (size_t)row * K + kbase + c0, Bs + row * BK + c0);
    }
    __syncthreads();
#pragma unroll
    for (int ks = 0; ks < 2; ++ks) {
      const int ko = ks * 32 + (lane >> 4) * 8;
      f16x8 af[4], bf[4];
#pragma unroll
      for (int i = 0; i < 4; ++i)
        af[i] = *(const f16x8*)(As + (wr * 64 + i * 16 + (lane & 15)) * BK + ko);
#pragma unroll
      for (int i = 0; i < 4; ++i)
        bf[i] = *(const f16x8*)(Bs + (wc * 64 + i * 16 + (lane & 15)) * BK + ko);
#pragma unroll
      for (int i = 0; i < 4; ++i)
#pragma unroll
        for (int j = 0; j < 4; ++j)
          acc[i][j] = __builtin_amdgcn_mfma_f32_16x16x32_f16(af[i], bf[j], acc[i][j], 0, 0, 0);
    }
    __syncthreads();
  }

  const int er = (lane >> 4) * 4;
  const int ec = lane & 15;
#pragma unroll
  for (int i = 0; i < 4; ++i) {
#pragma unroll
    for (int j = 0; j < 4; ++j) {
      const int gc = bn * 128 + wc * 64 + j * 16 + ec;
      const float bv = bias[gc];
      const size_t rbase = (size_t)(bm * 128 + wr * 64 + i * 16 + er);
      if (MODE == 0) {
#pragma unroll
        for (int r = 0; r < 4; ++r) {
          float v = acc[i][j][r] + bv;
          out0[(rbase + r) * D_ + gc] = (f16)v;
        }
      } else {
        const int seg = gc >> 9;
        const int cc = gc & 511;
#pragma unroll
        for (int r = 0; r < 4; ++r) {
          float v = acc[i][j][r] + bv;
          if (seg == 0) {
            out0[(rbase + r) * D_ + cc] = (f16)v;
          } else if (seg == 1) {
            float s = __builtin_amdgcn_rcpf(1.f + __expf(-v));
            out1[(rbase + r) * D_ + cc] = (f16)s;
          } else {
            float vc = fminf(fmaxf(v, -15.f), 15.f);
            float t = __expf(2.f * vc);
            float th = (t - 1.f) * __builtin_amdgcn_rcpf(t + 1.f);
            out2[(rbase + r) * D_ + cc] = (f16)th;
          }
        }
      }
    }
  }
}

// ---------------- scores (q.k^T / sqrt(D)) + softmax over m ----------------
// grid (B, 2): each block does 64 q-rows of one batch; 4 waves x 16 rows.
__global__ __launch_bounds__(256, 2)
void scores_softmax(const f16* __restrict__ q16, const f16* __restrict__ k16,
                    float* __restrict__ attn)
{
  __shared__ f16 Qs[64 * 64];
  __shared__ f16 Ks[96 * 64];
  const int b = blockIdx.x;
  const int wt = blockIdx.y;
  const int tid = threadIdx.x, lane = tid & 63, wv = tid >> 6;
  const f16* Qb = q16 + ((size_t)b * W_ + wt * 64) * D_;
  const f16* Kb = k16 + (size_t)b * M_ * D_;
  f32x4 acc[6] = {};
  const int r0 = tid >> 3, c0 = (tid & 7) * 8;

  for (int kk = 0; kk < 8; ++kk) {
    const int kbase = kk * 64;
#pragma unroll
    for (int p = 0; p < 2; ++p) {
      int row = p * 32 + r0;
      gload_lds16(Qb + (size_t)row * D_ + kbase + c0, Qs + row * 64 + c0);
    }
#pragma unroll
    for (int p = 0; p < 3; ++p) {
      int row = p * 32 + r0;
      gload_lds16(Kb + (size_t)row * D_ + kbase + c0, Ks + row * 64 + c0);
    }
    __syncthreads();
#pragma unroll
    for (int ks = 0; ks < 2; ++ks) {
      const int ko = ks * 32 + (lane >> 4) * 8;
      f16x8 aq = *(const f16x8*)(Qs + (wv * 16 + (lane & 15)) * 64 + ko);
#pragma unroll
      for (int j = 0; j < 6; ++j) {
        f16x8 bk8 = *(const f16x8*)(Ks + (j * 16 + (lane & 15)) * 64 + ko);
        acc[j] = __builtin_amdgcn_mfma_f32_16x16x32_f16(aq, bk8, acc[j], 0, 0, 0);
      }
    }
    __syncthreads();
  }

  const float scale = 0.04419417382415922f;  // 1/sqrt(512)
  const int er = (lane >> 4) * 4, ec = lane & 15;
#pragma unroll
  for (int r = 0; r < 4; ++r) {
    const int row = wt * 64 + wv * 16 + er + r;
    float s[6];
    float mx = -1e30f;
#pragma unroll
    for (int j = 0; j < 6; ++j) { s[j] = acc[j][r] * scale; mx = fmaxf(mx, s[j]); }
#pragma unroll
    for (int o = 1; o < 16; o <<= 1) mx = fmaxf(mx, __shfl_xor(mx, o));
    float sum = 0.f;
#pragma unroll
    for (int j = 0; j < 6; ++j) { s[j] = __expf(s[j] - mx); sum += s[j]; }
#pragma unroll
    for (int o = 1; o < 16; o <<= 1) sum += __shfl_xor(sum, o);
    const float inv = 1.f / sum;
#pragma unroll
    for (int j = 0; j < 6; ++j)
      attn[((size_t)b * W_ + row) * M_ + j * 16 + ec] = s[j] * inv;
  }
}

// ---------------- sequential erase/add scan over W + LayerNorm ----------------
// grid 768 = B*3; block handles (b, 32-row m-tile); thread owns 2 d x 32 m.
__global__ __launch_bounds__(256, 2)
void scan_ln(const float* __restrict__ memory, const f16* __restrict__ e16,
             const f16* __restrict__ a16, const float* __restrict__ attn,
             const float* __restrict__ gamma, const float* __restrict__ beta,
             float* __restrict__ out)
{
  __shared__ float a_s[32 * 32];
  __shared__ float red[32 * 8];
  __shared__ float mu_s[32], rs_s[32];
  const int blk = blockIdx.x;
  const int swz = (blk & 7) * 96 + (blk >> 3);   // 768 % 8 == 0 -> bijective
  const int b = swz / 3, mt = (swz % 3) * 32;
  const int tid = threadIdx.x;
  const int d0 = tid * 2;

  float2 acc[32];
  const float* memb = memory + ((size_t)b * M_ + mt) * D_ + d0;
#pragma unroll
  for (int m = 0; m < 32; ++m) acc[m] = *(const float2*)(memb + (size_t)m * D_);

  const f16* eb = e16 + (size_t)b * W_ * D_ + d0;
  const f16* ab = a16 + (size_t)b * W_ * D_ + d0;
  const float* atb = attn + (size_t)b * W_ * M_ + mt;

  for (int wch = 0; wch < 4; ++wch) {
    __syncthreads();
    {
      const int rr = tid >> 5, cc = tid & 31;
#pragma unroll
      for (int j = 0; j < 4; ++j) {
        int w = rr + 8 * j;
        a_s[w * 32 + cc] = atb[(size_t)(wch * 32 + w) * M_ + cc];
      }
    }
    __syncthreads();
    for (int wi = 0; wi < 32; ++wi) {
      const int w = wch * 32 + wi;
      f16x2 ev = *(const f16x2*)(eb + (size_t)w * D_);
      f16x2 av2 = *(const f16x2*)(ab + (size_t)w * D_);
      float ex = (float)ev.x, ey = (float)ev.y;
      float ax = (float)av2.x, ay = (float)av2.y;
      const float4* ap = (const float4*)(a_s + wi * 32);
      float aw[32];
#pragma unroll
      for (int j = 0; j < 8; ++j) {
        float4 t = ap[j];
        aw[4 * j] = t.x; aw[4 * j + 1] = t.y; aw[4 * j + 2] = t.z; aw[4 * j + 3] = t.w;
      }
#pragma unroll
      for (int m = 0; m < 32; ++m) {
        float a = aw[m];
        acc[m].x = fmaf(acc[m].x, fmaf(-a, ex, 1.f), a * ax);
        acc[m].y = fmaf(acc[m].y, fmaf(-a, ey, 1.f), a * ay);
      }
    }
  }

  // LayerNorm over d (512) per m-row
  const int lane = tid & 63, wv = tid >> 6;
#pragma unroll
  for (int m = 0; m < 32; ++m) {
    float s = acc[m].x + acc[m].y;
    float q = acc[m].x * acc[m].x + acc[m].y * acc[m].y;
#pragma unroll
    for (int o = 1; o < 64; o <<= 1) { s += __shfl_xor(s, o); q += __shfl_xor(q, o); }
    if (lane == 0) { red[m * 8 + wv] = s; red[m * 8 + 4 + wv] = q; }
  }
  __syncthreads();
  if (tid < 32) {
    float s = red[tid * 8] + red[tid * 8 + 1] + red[tid * 8 + 2] + red[tid * 8 + 3];
    float q = red[tid * 8 + 4] + red[tid * 8 + 5] + red[tid * 8 + 6] + red[tid * 8 + 7];
    float mu = s * (1.f / 512.f);
    float var = q * (1.f / 512.f) - mu * mu;
    mu_s[tid] = mu;
    rs_s[tid] = rsqrtf(var + 1e-5f);
  }
  __syncthreads();
  const float gx = gamma[d0], gy = gamma[d0 + 1];
  const float bx = beta[d0], by = beta[d0 + 1];
  float* ob = out + ((size_t)b * M_ + mt) * D_ + d0;
#pragma unroll
  for (int m = 0; m < 32; ++m) {
    float mu = mu_s[m], rs = rs_s[m];
    float2 o;
    o.x = (acc[m].x - mu) * rs * gx + bx;
    o.y = (acc[m].y - mu) * rs * gy + by;
    *(float2*)(ob + (size_t)m * D_) = o;
  }
}

// ---------------- launcher ----------------
extern "C" void kernel_launch(void* const* d_in, const int* in_sizes, int n_in,
                              void* d_out, int out_size, void* d_ws, size_t ws_size,
                              hipStream_t stream)
{
  const float* memory = (const float*)d_in[0];
  const float* wtok   = (const float*)d_in[1];
  const float* Wq = (const float*)d_in[2];
  const float* bq = (const float*)d_in[3];
  const float* Wk = (const float*)d_in[4];
  const float* bk = (const float*)d_in[5];
  const float* We = (const float*)d_in[6];
  const float* ba_e = (const float*)d_in[7];
  const float* Wa = (const float*)d_in[8];
  const float* ba_a = (const float*)d_in[9];
  const float* gamma = (const float*)d_in[10];
  const float* beta  = (const float*)d_in[11];
  float* out = (float*)d_out;

  uint8_t* ws = (uint8_t*)d_ws;
  size_t off = 0;
  auto alloc = [&](size_t bytes) -> void* {
    void* p = ws + off;
    off += (bytes + 255) & ~(size_t)255;
    return p;
  };
  f16* wt16   = (f16*)alloc((size_t)B_ * W_ * D_ * 2);
  f16* mem16  = (f16*)alloc((size_t)B_ * M_ * D_ * 2);
  f16* wqea16 = (f16*)alloc((size_t)3 * D_ * D_ * 2);
  f16* wk16   = (f16*)alloc((size_t)D_ * D_ * 2);
  f16* q16    = (f16*)alloc((size_t)B_ * W_ * D_ * 2);
  f16* k16    = (f16*)alloc((size_t)B_ * M_ * D_ * 2);
  f16* e16    = (f16*)alloc((size_t)B_ * W_ * D_ * 2);
  f16* a16    = (f16*)alloc((size_t)B_ * W_ * D_ * 2);
  float* attn = (float*)alloc((size_t)B_ * W_ * M_ * 4);
  float* bqea = (float*)alloc(3 * D_ * 4);
  (void)ws_size; (void)in_sizes; (void)n_in; (void)out_size;

  // concat biases bq|be|ba for the fused QEA GEMM
  hipMemcpyAsync(bqea,            bq,   D_ * 4, hipMemcpyDeviceToDevice, stream);
  hipMemcpyAsync(bqea + D_,       ba_e, D_ * 4, hipMemcpyDeviceToDevice, stream);
  hipMemcpyAsync(bqea + 2 * D_,   ba_a, D_ * 4, hipMemcpyDeviceToDevice, stream);

  const int n8wt = B_ * W_ * D_ / 8;   // 2,097,152
  const int n8m  = B_ * M_ * D_ / 8;   // 1,572,864
  const int n8w  = D_ * D_ / 8;        // 32,768
  cvt_f32_f16<<<n8wt / 256, 256, 0, stream>>>(wtok, wt16, n8wt);
  cvt_f32_f16<<<n8m / 256, 256, 0, stream>>>(memory, mem16, n8m);
  cvt_f32_f16<<<n8w / 256, 256, 0, stream>>>(Wq, wqea16, n8w);
  cvt_f32_f16<<<n8w / 256, 256, 0, stream>>>(We, wqea16 + (size_t)D_ * D_, n8w);
  cvt_f32_f16<<<n8w / 256, 256, 0, stream>>>(Wa, wqea16 + (size_t)2 * D_ * D_, n8w);
  cvt_f32_f16<<<n8w / 256, 256, 0, stream>>>(Wk, wk16, n8w);

  // q / erase / add fused GEMM: [32768, 512] x [512, 1536]
  gemm_bt<1><<<dim3(B_ * W_ / 128, 12), 256, 0, stream>>>(wt16, wqea16, bqea, q16, e16, a16);
  // k GEMM: [24576, 512] x [512, 512]
  gemm_bt<0><<<dim3(B_ * M_ / 128, 4), 256, 0, stream>>>(mem16, wk16, bk, k16, nullptr, nullptr);
  // scores + softmax
  scores_softmax<<<dim3(B_, 2), 256, 0, stream>>>(q16, k16, attn);
  // sequential scan + LayerNorm
  scan_ln<<<dim3(B_ * 3), 256, 0, stream>>>(memory, e16, a16, attn, gamma, beta, out);
}

// Round 2
// 379.893 us; speedup vs baseline: 1.1051x; 1.1051x over previous
//
#include <hip/hip_runtime.h>
#include <cstdint>
#include <cstddef>

#define B_ 256
#define M_ 96
#define W_ 128
#define D_ 512

typedef _Float16 f16;
typedef __attribute__((ext_vector_type(8))) _Float16 f16x8;
typedef __attribute__((ext_vector_type(2))) _Float16 f16x2;
typedef __attribute__((ext_vector_type(4))) float f32x4;
typedef __attribute__((ext_vector_type(16))) float f32x16;

typedef __attribute__((address_space(3))) void lds_void;
typedef const __attribute__((address_space(1))) void glb_void;

__device__ __forceinline__ void gload_lds16(const void* g, void* l) {
  __builtin_amdgcn_global_load_lds((glb_void*)g, (lds_void*)l, 16, 0, 0);
}

// Wave-uniform scalar load of two attn rows (16 floats each, rows 384B apart).
// SMEM returns can complete out-of-order -> only lgkmcnt(0) is safe; the wait
// is a separate asm block with "+s" ties so consumers can't be hoisted (rule #18).
__device__ __forceinline__ void sload_rows2(const float* p, f32x16& a, f32x16& b) {
  asm volatile(
      "s_load_dwordx16 %0, %2, 0x0\n\t"
      "s_load_dwordx16 %1, %2, 0x180"
      : "=s"(a), "=s"(b)
      : "s"(p));
}
__device__ __forceinline__ void swait2(f32x16& a, f32x16& b) {
  asm volatile("s_waitcnt lgkmcnt(0)" : "+s"(a), "+s"(b));
}

// ---------------- fused f32 -> f16 conversions ----------------
__global__ void cvt_act(const float* __restrict__ wtok, f16* __restrict__ wt16,
                        const float* __restrict__ mem, f16* __restrict__ mem16) {
  const int bid = blockIdx.x;
  const float* in;
  f16* out;
  int i;
  if (bid < 8192) { in = wtok; out = wt16; i = bid * 256 + threadIdx.x; }
  else            { in = mem;  out = mem16; i = (bid - 8192) * 256 + threadIdx.x; }
  const float4* p = (const float4*)in + (size_t)i * 2;
  float4 a = p[0], b = p[1];
  f16x8 o = { (f16)a.x, (f16)a.y, (f16)a.z, (f16)a.w,
              (f16)b.x, (f16)b.y, (f16)b.z, (f16)b.w };
  ((f16x8*)out)[i] = o;
}

// 4 weight matrices (Wq, We, Wa, Wk) into one contiguous f16 buffer
__global__ void cvt_w(const float* __restrict__ w0, const float* __restrict__ w1,
                      const float* __restrict__ w2, const float* __restrict__ w3,
                      f16* __restrict__ out) {
  const int bid = blockIdx.x;
  const int g = bid >> 7;                 // 128 blocks per matrix
  const int il = (bid & 127) * 256 + threadIdx.x;
  const float* src = (g == 0) ? w0 : (g == 1) ? w1 : (g == 2) ? w2 : w3;
  const float4* p = (const float4*)src + (size_t)il * 2;
  float4 a = p[0], b = p[1];
  f16x8 o = { (f16)a.x, (f16)a.y, (f16)a.z, (f16)a.w,
              (f16)b.x, (f16)b.y, (f16)b.z, (f16)b.w };
  ((f16x8*)out)[(size_t)g * 32768 + il] = o;
}

// ---------------- BT GEMM, 128x128 tile, BK=64, f16 MFMA ----------------
// MODE 0: out0 = (f16)(acc + bias0[col])                       (k GEMM)
// MODE 1: cols [0,512): q + bias0 -> out0 ; [512,1024): sigmoid(.+bias1) -> out1 ;
//         [1024,1536): tanh(.+bias2) -> out2
template<int MODE>
__global__ __launch_bounds__(256, 2)
void gemm_bt(const f16* __restrict__ A, const f16* __restrict__ Bm,
             const float* __restrict__ bias0, const float* __restrict__ bias1,
             const float* __restrict__ bias2,
             f16* __restrict__ out0, f16* __restrict__ out1, f16* __restrict__ out2)
{
  constexpr int K = 512;
  constexpr int BK = 64;
  __shared__ f16 As[128 * BK];
  __shared__ f16 Bs[128 * BK];
  const int tid = threadIdx.x;
  const int lane = tid & 63;
  const int wv = tid >> 6;
  const int wr = wv >> 1, wc = wv & 1;
  const int bm = blockIdx.x, bn = blockIdx.y;
  const f16* Ab = A + (size_t)bm * 128 * K;
  const f16* Bb = Bm + (size_t)bn * 128 * K;

  f32x4 acc[4][4] = {};

  const int r0 = tid >> 3;
  const int c0 = (tid & 7) * 8;

  for (int kk = 0; kk < K / BK; ++kk) {
    const int kbase = kk * BK;
#pragma unroll
    for (int p = 0; p < 4; ++p) {
      int row = p * 32 + r0;
      gload_lds16(Ab + (size_t)row * K + kbase + c0, As + row * BK + c0);
    }
#pragma unroll
    for (int p = 0; p < 4; ++p) {
      int row = p * 32 + r0;
      gload_lds16(Bb + (size_t)row * K + kbase + c0, Bs + row * BK + c0);
    }
    __syncthreads();
#pragma unroll
    for (int ks = 0; ks < 2; ++ks) {
      const int ko = ks * 32 + (lane >> 4) * 8;
      f16x8 af[4], bf[4];
#pragma unroll
      for (int i = 0; i < 4; ++i)
        af[i] = *(const f16x8*)(As + (wr * 64 + i * 16 + (lane & 15)) * BK + ko);
#pragma unroll
      for (int i = 0; i < 4; ++i)
        bf[i] = *(const f16x8*)(Bs + (wc * 64 + i * 16 + (lane & 15)) * BK + ko);
#pragma unroll
      for (int i = 0; i < 4; ++i)
#pragma unroll
        for (int j = 0; j < 4; ++j)
          acc[i][j] = __builtin_amdgcn_mfma_f32_16x16x32_f16(af[i], bf[j], acc[i][j], 0, 0, 0);
    }
    __syncthreads();
  }

  const int er = (lane >> 4) * 4;
  const int ec = lane & 15;
#pragma unroll
  for (int i = 0; i < 4; ++i) {
#pragma unroll
    for (int j = 0; j < 4; ++j) {
      const int gc = bn * 128 + wc * 64 + j * 16 + ec;
      const size_t rbase = (size_t)(bm * 128 + wr * 64 + i * 16 + er);
      if (MODE == 0) {
        const float bv = bias0[gc];
#pragma unroll
        for (int r = 0; r < 4; ++r) {
          float v = acc[i][j][r] + bv;
          out0[(rbase + r) * D_ + gc] = (f16)v;
        }
      } else {
        const int seg = gc >> 9;
        const int cc = gc & 511;
        const float* bp = (seg == 0) ? bias0 : (seg == 1) ? bias1 : bias2;
        const float bv = bp[cc];
#pragma unroll
        for (int r = 0; r < 4; ++r) {
          float v = acc[i][j][r] + bv;
          if (seg == 0) {
            out0[(rbase + r) * D_ + cc] = (f16)v;
          } else if (seg == 1) {
            float s = __builtin_amdgcn_rcpf(1.f + __expf(-v));
            out1[(rbase + r) * D_ + cc] = (f16)s;
          } else {
            float vc = fminf(fmaxf(v, -15.f), 15.f);
            float t = __expf(2.f * vc);
            float th = (t - 1.f) * __builtin_amdgcn_rcpf(t + 1.f);
            out2[(rbase + r) * D_ + cc] = (f16)th;
          }
        }
      }
    }
  }
}

// ---------------- scores (q.k^T / sqrt(D)) + softmax over m ----------------
__global__ __launch_bounds__(256, 2)
void scores_softmax(const f16* __restrict__ q16, const f16* __restrict__ k16,
                    float* __restrict__ attn)
{
  __shared__ f16 Qs[64 * 64];
  __shared__ f16 Ks[96 * 64];
  const int b = blockIdx.x;
  const int wt = blockIdx.y;
  const int tid = threadIdx.x, lane = tid & 63, wv = tid >> 6;
  const f16* Qb = q16 + ((size_t)b * W_ + wt * 64) * D_;
  const f16* Kb = k16 + (size_t)b * M_ * D_;
  f32x4 acc[6] = {};
  const int r0 = tid >> 3, c0 = (tid & 7) * 8;

  for (int kk = 0; kk < 8; ++kk) {
    const int kbase = kk * 64;
#pragma unroll
    for (int p = 0; p < 2; ++p) {
      int row = p * 32 + r0;
      gload_lds16(Qb + (size_t)row * D_ + kbase + c0, Qs + row * 64 + c0);
    }
#pragma unroll
    for (int p = 0; p < 3; ++p) {
      int row = p * 32 + r0;
      gload_lds16(Kb + (size_t)row * D_ + kbase + c0, Ks + row * 64 + c0);
    }
    __syncthreads();
#pragma unroll
    for (int ks = 0; ks < 2; ++ks) {
      const int ko = ks * 32 + (lane >> 4) * 8;
      f16x8 aq = *(const f16x8*)(Qs + (wv * 16 + (lane & 15)) * 64 + ko);
#pragma unroll
      for (int j = 0; j < 6; ++j) {
        f16x8 bk8 = *(const f16x8*)(Ks + (j * 16 + (lane & 15)) * 64 + ko);
        acc[j] = __builtin_amdgcn_mfma_f32_16x16x32_f16(aq, bk8, acc[j], 0, 0, 0);
      }
    }
    __syncthreads();
  }

  const float scale = 0.04419417382415922f;  // 1/sqrt(512)
  const int er = (lane >> 4) * 4, ec = lane & 15;
#pragma unroll
  for (int r = 0; r < 4; ++r) {
    const int row = wt * 64 + wv * 16 + er + r;
    float s[6];
    float mx = -1e30f;
#pragma unroll
    for (int j = 0; j < 6; ++j) { s[j] = acc[j][r] * scale; mx = fmaxf(mx, s[j]); }
#pragma unroll
    for (int o = 1; o < 16; o <<= 1) mx = fmaxf(mx, __shfl_xor(mx, o));
    float sum = 0.f;
#pragma unroll
    for (int j = 0; j < 6; ++j) { s[j] = __expf(s[j] - mx); sum += s[j]; }
#pragma unroll
    for (int o = 1; o < 16; o <<= 1) sum += __shfl_xor(sum, o);
    const float inv = 1.f / sum;
#pragma unroll
    for (int j = 0; j < 6; ++j)
      attn[((size_t)b * W_ + row) * M_ + j * 16 + ec] = s[j] * inv;
  }
}

// ---------------- sequential erase/add scan over W + LayerNorm ----------------
// grid 1536 = B*6; block = (b, 16-row m-tile); thread owns 2 d x 16 m.
// attn row is block-uniform -> SGPRs via s_load; acc stays in VGPRs (32).
__global__ __launch_bounds__(256, 6)
void scan_ln(const float* __restrict__ memory, const f16* __restrict__ e16,
             const f16* __restrict__ a16, const float* __restrict__ attn,
             const float* __restrict__ gamma, const float* __restrict__ beta,
             float* __restrict__ out)
{
  __shared__ float red[16 * 8];
  __shared__ float mu_s[16], rs_s[16];
  const int blk = blockIdx.x;
  const int swz = (blk & 7) * 192 + (blk >> 3);   // 1536 % 8 == 0 -> bijective
  const int b = swz / 6, mt = (swz % 6) * 16;
  const int tid = threadIdx.x;
  const int d0 = tid * 2;

  float2 acc[16];
  const float* memb = memory + ((size_t)b * M_ + mt) * D_ + d0;
#pragma unroll
  for (int m = 0; m < 16; ++m) acc[m] = *(const float2*)(memb + (size_t)m * D_);

  const f16* eb = e16 + (size_t)b * W_ * D_ + d0;
  const f16* ab = a16 + (size_t)b * W_ * D_ + d0;
  const float* atb = attn + (size_t)b * W_ * M_ + mt;

  // preload e/ad for w=0,1
  float2 ev0, av0, ev1, av1;
  {
    f16x2 e0 = *(const f16x2*)(eb);
    f16x2 a0 = *(const f16x2*)(ab);
    f16x2 e1 = *(const f16x2*)(eb + D_);
    f16x2 a1 = *(const f16x2*)(ab + D_);
    ev0 = { (float)e0.x, (float)e0.y }; av0 = { (float)a0.x, (float)a0.y };
    ev1 = { (float)e1.x, (float)e1.y }; av1 = { (float)a1.x, (float)a1.y };
  }

  for (int w = 0; w < W_; w += 2) {
    f32x16 r0, r1;
    sload_rows2(atb + (size_t)w * M_, r0, r1);

    // prefetch e/ad for next pair (clamped; value unused on last iter)
    const int wn = (w + 2 < W_) ? (w + 2) : (W_ - 2);
    f16x2 e0 = *(const f16x2*)(eb + (size_t)wn * D_);
    f16x2 a0 = *(const f16x2*)(ab + (size_t)wn * D_);
    f16x2 e1 = *(const f16x2*)(eb + (size_t)(wn + 1) * D_);
    f16x2 a1 = *(const f16x2*)(ab + (size_t)(wn + 1) * D_);

    swait2(r0, r1);
#pragma unroll
    for (int m = 0; m < 16; ++m) {
      float a = r0[m];
      acc[m].x = fmaf(a, fmaf(-ev0.x, acc[m].x, av0.x), acc[m].x);
      acc[m].y = fmaf(a, fmaf(-ev0.y, acc[m].y, av0.y), acc[m].y);
    }
#pragma unroll
    for (int m = 0; m < 16; ++m) {
      float a = r1[m];
      acc[m].x = fmaf(a, fmaf(-ev1.x, acc[m].x, av1.x), acc[m].x);
      acc[m].y = fmaf(a, fmaf(-ev1.y, acc[m].y, av1.y), acc[m].y);
    }
    ev0 = { (float)e0.x, (float)e0.y }; av0 = { (float)a0.x, (float)a0.y };
    ev1 = { (float)e1.x, (float)e1.y }; av1 = { (float)a1.x, (float)a1.y };
  }

  // LayerNorm over d (512) per m-row
  const int lane = tid & 63, wv = tid >> 6;
#pragma unroll
  for (int m = 0; m < 16; ++m) {
    float s = acc[m].x + acc[m].y;
    float q = fmaf(acc[m].x, acc[m].x, acc[m].y * acc[m].y);
#pragma unroll
    for (int o = 1; o < 64; o <<= 1) { s += __shfl_xor(s, o); q += __shfl_xor(q, o); }
    if (lane == 0) { red[m * 8 + wv] = s; red[m * 8 + 4 + wv] = q; }
  }
  __syncthreads();
  if (tid < 16) {
    float s = red[tid * 8] + red[tid * 8 + 1] + red[tid * 8 + 2] + red[tid * 8 + 3];
    float q = red[tid * 8 + 4] + red[tid * 8 + 5] + red[tid * 8 + 6] + red[tid * 8 + 7];
    float mu = s * (1.f / 512.f);
    float var = q * (1.f / 512.f) - mu * mu;
    mu_s[tid] = mu;
    rs_s[tid] = rsqrtf(var + 1e-5f);
  }
  __syncthreads();
  const float gx = gamma[d0], gy = gamma[d0 + 1];
  const float bx = beta[d0], by = beta[d0 + 1];
  float* ob = out + ((size_t)b * M_ + mt) * D_ + d0;
#pragma unroll
  for (int m = 0; m < 16; ++m) {
    float mu = mu_s[m], rs = rs_s[m];
    float2 o;
    o.x = (acc[m].x - mu) * rs * gx + bx;
    o.y = (acc[m].y - mu) * rs * gy + by;
    *(float2*)(ob + (size_t)m * D_) = o;
  }
}

// ---------------- launcher ----------------
extern "C" void kernel_launch(void* const* d_in, const int* in_sizes, int n_in,
                              void* d_out, int out_size, void* d_ws, size_t ws_size,
                              hipStream_t stream)
{
  const float* memory = (const float*)d_in[0];
  const float* wtok   = (const float*)d_in[1];
  const float* Wq = (const float*)d_in[2];
  const float* bq = (const float*)d_in[3];
  const float* Wk = (const float*)d_in[4];
  const float* bk = (const float*)d_in[5];
  const float* We = (const float*)d_in[6];
  const float* be = (const float*)d_in[7];
  const float* Wa = (const float*)d_in[8];
  const float* ba = (const float*)d_in[9];
  const float* gamma = (const float*)d_in[10];
  const float* beta  = (const float*)d_in[11];
  float* out = (float*)d_out;

  uint8_t* ws = (uint8_t*)d_ws;
  size_t off = 0;
  auto alloc = [&](size_t bytes) -> void* {
    void* p = ws + off;
    off += (bytes + 255) & ~(size_t)255;
    return p;
  };
  f16* wt16   = (f16*)alloc((size_t)B_ * W_ * D_ * 2);
  f16* mem16  = (f16*)alloc((size_t)B_ * M_ * D_ * 2);
  f16* w16    = (f16*)alloc((size_t)4 * D_ * D_ * 2);   // Wq|We|Wa|Wk
  f16* q16    = (f16*)alloc((size_t)B_ * W_ * D_ * 2);
  f16* k16    = (f16*)alloc((size_t)B_ * M_ * D_ * 2);
  f16* e16    = (f16*)alloc((size_t)B_ * W_ * D_ * 2);
  f16* a16    = (f16*)alloc((size_t)B_ * W_ * D_ * 2);
  float* attn = (float*)alloc((size_t)B_ * W_ * M_ * 4);
  (void)ws_size; (void)in_sizes; (void)n_in; (void)out_size;

  f16* wqea16 = w16;                       // 3*D*D
  f16* wk16   = w16 + (size_t)3 * D_ * D_; // 1*D*D

  // conversions: 2 launches
  cvt_act<<<dim3(8192 + 6144), 256, 0, stream>>>(wtok, wt16, memory, mem16);
  cvt_w<<<dim3(512), 256, 0, stream>>>(Wq, We, Wa, Wk, w16);

  // q / erase / add fused GEMM: [32768, 512] x [512, 1536]
  gemm_bt<1><<<dim3(B_ * W_ / 128, 12), 256, 0, stream>>>(wt16, wqea16, bq, be, ba, q16, e16, a16);
  // k GEMM: [24576, 512] x [512, 512]
  gemm_bt<0><<<dim3(B_ * M_ / 128, 4), 256, 0, stream>>>(mem16, wk16, bk, nullptr, nullptr, k16, nullptr, nullptr);
  // scores + softmax
  scores_softmax<<<dim3(B_, 2), 256, 0, stream>>>(q16, k16, attn);
  // sequential scan + LayerNorm
  scan_ln<<<dim3(B_ * 6), 256, 0, stream>>>(memory, e16, a16, attn, gamma, beta, out);
}